// Round 4
// baseline (598.521 us; speedup 1.0000x reference)
//
#include <hip/hip_runtime.h>
#include <cfloat>
#include <cstdint>

// Problem constants (YOLOv8 640x640 head)
#define NB 64
#define NG 32
#define NC 80
#define NA 8400
#define KTOP 13
#define CHUNK 512
#define NCH 17                 // ceil(NA/CHUNK)
#define NCAND (NCH * KTOP)     // 221 candidates per (b,g)

// ---------------------------------------------------------------------------
// Fused A+B: per block = (chunk of 512 anchors, batch b).
// Phase 1: decode pred box, softmax, IoU/align vs 32 GTs -> align in LDS.
//          Also writes pb (float4), (mx, 1/denom) (float2), inside32, bestg.
// Phase 2: wave-per-g top-13 within the chunk -> candidate buffer.
// NO atomics, no zeroed scatter buffers.
// ---------------------------------------------------------------------------
__global__ __launch_bounds__(256) void fusedAB(
    const float* __restrict__ preds,          // (B, 84, A)
    const float* __restrict__ gt_bboxes,      // (B, G, 4)
    const int*   __restrict__ gt_classes,     // (B, G)
    const float* __restrict__ anchor_points,  // (A, 2)
    float4*      __restrict__ pb_ws,          // (B*A) decoded boxes
    float2*      __restrict__ aux_ws,         // (B*A) (mx, rdenom)
    unsigned*    __restrict__ inside32,       // (B*A)
    int*         __restrict__ bestg,          // (B*A)
    float*       __restrict__ candv,          // (B*G, NCH, 13)
    int*         __restrict__ candi,          // (B*G, NCH, 13)
    float*       __restrict__ out_sum)        // scalar, zeroed here
{
    __shared__ float sx1[NG], sy1[NG], sx2[NG], sy2[NG], sarea[NG];
    __shared__ int   scls[NG];
    __shared__ float salign[NG][CHUNK];       // 64 KB

    const int tid   = threadIdx.x;
    const int chunk = blockIdx.x;
    const int b     = blockIdx.y;
    const int abase = chunk * CHUNK;
    const int a0    = abase + tid * 2;        // 2 anchors per thread (NA even)

    if (tid < NG) {
        const float* gb = gt_bboxes + ((size_t)b * NG + tid) * 4;
        const float x1 = gb[0], y1 = gb[1], x2 = gb[2], y2 = gb[3];
        sx1[tid] = x1; sy1[tid] = y1; sx2[tid] = x2; sy2[tid] = y2;
        sarea[tid] = (x2 - x1) * (y2 - y1);
        scls[tid]  = gt_classes[b * NG + tid];
    }
    if (b == 0 && chunk == 0 && tid == 0) out_sum[0] = 0.0f;
    __syncthreads();

    if (a0 < NA) {
        const float4 ap = *(const float4*)(anchor_points + (size_t)a0 * 2);
        const float axA = ap.x, ayA = ap.y, axB = ap.z, ayB = ap.w;

        const float* db = preds + (size_t)b * (4 + NC) * NA + a0;
        const float2 dl = *(const float2*)(db);
        const float2 dt = *(const float2*)(db + (size_t)NA);
        const float2 dr = *(const float2*)(db + (size_t)2 * NA);
        const float2 dm = *(const float2*)(db + (size_t)3 * NA);
        const float x1A = axA - dl.x, y1A = ayA - dt.x, x2A = axA + dr.x, y2A = ayA + dm.x;
        const float x1B = axB - dl.y, y1B = ayB - dt.y, x2B = axB + dr.y, y2B = ayB + dm.y;
        const float areaA = (x2A - x1A) * (y2A - y1A);
        const float areaB = (x2B - x1B) * (y2B - y1B);

        const float* cb = db + (size_t)4 * NA;
        float mxA = -FLT_MAX, mxB = -FLT_MAX;
#pragma unroll 8
        for (int c = 0; c < NC; ++c) {
            const float2 v = *(const float2*)(cb + (size_t)c * NA);
            mxA = fmaxf(mxA, v.x); mxB = fmaxf(mxB, v.y);
        }
        float dA = 0.0f, dB = 0.0f;
#pragma unroll 8
        for (int c = 0; c < NC; ++c) {
            const float2 v = *(const float2*)(cb + (size_t)c * NA);
            dA += __expf(v.x - mxA); dB += __expf(v.y - mxB);
        }
        const float rdA = 1.0f / dA, rdB = 1.0f / dB;

        unsigned insA = 0u, insB = 0u;
        int bgA = 0, bgB = 0;
        float biA = -1.0f, biB = -1.0f;   // strict > keeps first max (jnp.argmax)

        for (int g = 0; g < NG; ++g) {
            const float bx1 = sx1[g], by1 = sy1[g], bx2 = sx2[g], by2 = sy2[g];
            const float sag = sarea[g];
            const float2 cv2 = *(const float2*)(cb + (size_t)scls[g] * NA);
            float alA, alB;
            {
                const float ltx = fmaxf(x1A, bx1), lty = fmaxf(y1A, by1);
                const float rbx = fminf(x2A, bx2), rby = fminf(y2A, by2);
                const float w = fmaxf(rbx - ltx, 0.0f), h = fmaxf(rby - lty, 0.0f);
                const float inter = w * h;
                const float iou = inter / (areaA + sag - inter + 1e-7f);
                if (iou > biA) { biA = iou; bgA = g; }
                const float cv = __expf(cv2.x - mxA) * rdA;
                alA = sqrtf(fmaxf(iou, 1e-12f)) * sqrtf(fmaxf(cv, 1e-12f));
                const float dmin = fminf(fminf(axA - bx1, ayA - by1), fminf(bx2 - axA, by2 - ayA));
                if (dmin > 1e-9f) insA |= (1u << g);
            }
            {
                const float ltx = fmaxf(x1B, bx1), lty = fmaxf(y1B, by1);
                const float rbx = fminf(x2B, bx2), rby = fminf(y2B, by2);
                const float w = fmaxf(rbx - ltx, 0.0f), h = fmaxf(rby - lty, 0.0f);
                const float inter = w * h;
                const float iou = inter / (areaB + sag - inter + 1e-7f);
                if (iou > biB) { biB = iou; bgB = g; }
                const float cv = __expf(cv2.y - mxB) * rdB;
                alB = sqrtf(fmaxf(iou, 1e-12f)) * sqrtf(fmaxf(cv, 1e-12f));
                const float dmin = fminf(fminf(axB - bx1, ayB - by1), fminf(bx2 - axB, by2 - ayB));
                if (dmin > 1e-9f) insB |= (1u << g);
            }
            *(float2*)&salign[g][tid * 2] = make_float2(alA, alB);
        }

        const int i0 = b * NA + a0;
        pb_ws[i0]     = make_float4(x1A, y1A, x2A, y2A);
        pb_ws[i0 + 1] = make_float4(x1B, y1B, x2B, y2B);
        aux_ws[i0]     = make_float2(mxA, rdA);
        aux_ws[i0 + 1] = make_float2(mxB, rdB);
        *(uint2*)&inside32[i0] = make_uint2(insA, insB);
        *(int2*)&bestg[i0]     = make_int2(bgA, bgB);
    }
    __syncthreads();

    // ---- Phase 2: wave w handles g = w*8 .. w*8+7; top-13 of 512 LDS values
    const int lane = tid & 63;
    const int wid  = tid >> 6;
    for (int gi = 0; gi < 8; ++gi) {
        const int g = wid * 8 + gi;
        float v[8]; int id[8];
#pragma unroll
        for (int j = 0; j < 8; ++j) { v[j] = -FLT_MAX; id[j] = 0x7FFFFFFF; }
        // lane sees exactly 8 slots (ascending index) -> list never overflows
#pragma unroll
        for (int k = 0; k < 8; ++k) {
            const int al = lane + 64 * k;
            const int a  = abase + al;
            const float x = (a < NA) ? salign[g][al] : -FLT_MAX;
            if (x > v[7]) {
                int j = 7;
                while (j > 0 && v[j - 1] < x) { v[j] = v[j - 1]; id[j] = id[j - 1]; --j; }
                v[j] = x; id[j] = a;
            }
        }
        float rv = -FLT_MAX; int ri = 0x7FFFFFFF;
        int p = 0;
        for (int r = 0; r < KTOP; ++r) {
            const float cvv = (p < 8) ? v[p]  : -FLT_MAX;
            const int   cii = (p < 8) ? id[p] : 0x7FFFFFFF;
            float bv = cvv; int bi = cii;
#pragma unroll
            for (int off = 32; off > 0; off >>= 1) {
                const float ov = __shfl_xor(bv, off, 64);
                const int   oi = __shfl_xor(bi, off, 64);
                if (ov > bv || (ov == bv && oi < bi)) { bv = ov; bi = oi; }
            }
            if (cii == bi && p < 8) ++p;   // unique ids -> exactly one lane pops
            if (lane == r) { rv = bv; ri = bi; }
        }
        if (lane < KTOP) {
            const size_t base = ((size_t)(b * NG + g) * NCH + chunk) * KTOP + lane;
            candv[base] = rv; candi[base] = ri;
        }
    }
}

// ---------------------------------------------------------------------------
// Merge: one wave per (b,g): merge NCH*13=221 candidates -> final top-13
// anchor indices, written as a dense list (plain stores, NO atomics).
// ---------------------------------------------------------------------------
__global__ __launch_bounds__(256) void mergeTopK(
    const float* __restrict__ candv,
    const int*   __restrict__ candi,
    int*         __restrict__ topk13)   // (B*G, 13)
{
    const int tid  = threadIdx.x;
    const int lane = tid & 63;
    const int row  = blockIdx.x * 4 + (tid >> 6);   // b*NG + g
    const size_t base = (size_t)row * NCAND;

    float v[4]; int id[4];
#pragma unroll
    for (int j = 0; j < 4; ++j) { v[j] = -FLT_MAX; id[j] = 0x7FFFFFFF; }
    // lane sees <=4 candidates; lex insertion (val desc, idx asc)
#pragma unroll
    for (int k = 0; k < 4; ++k) {
        const int j0 = lane + 64 * k;
        if (j0 < NCAND) {
            const float x  = candv[base + j0];
            const int   xi = candi[base + j0];
            int j = 3;
            while (j > 0 && (v[j - 1] < x || (v[j - 1] == x && id[j - 1] > xi))) {
                v[j] = v[j - 1]; id[j] = id[j - 1]; --j;
            }
            v[j] = x; id[j] = xi;
        }
    }
    int ri = 0x7FFFFFFF;
    int p = 0;
    for (int r = 0; r < KTOP; ++r) {
        const float cvv = (p < 4) ? v[p]  : -FLT_MAX;
        const int   cii = (p < 4) ? id[p] : 0x7FFFFFFF;
        float bv = cvv; int bi = cii;
#pragma unroll
        for (int off = 32; off > 0; off >>= 1) {
            const float ov = __shfl_xor(bv, off, 64);
            const int   oi = __shfl_xor(bi, off, 64);
            if (ov > bv || (ov == bv && oi < bi)) { bv = ov; bi = oi; }
        }
        if (cii == bi && p < 4) ++p;
        if (lane == r) ri = bi;
    }
    if (lane < KTOP) topk13[(size_t)row * KTOP + lane] = ri;
}

// ---------------------------------------------------------------------------
// Phase C: grid (33, B). Block loads its batch's 32x13 winner indices into
// LDS; each anchor thread rebuilds its selection mask by scanning them.
// out layout: tb (B,A,4) | tc (B,A) | ts (B,A) | fg (B,A) | fg_sum (1)
// ---------------------------------------------------------------------------
__global__ __launch_bounds__(256) void phaseC(
    const float*    __restrict__ gt_bboxes,
    const int*      __restrict__ gt_classes,
    const float*    __restrict__ preds,
    const float4*   __restrict__ pb_ws,
    const float2*   __restrict__ aux_ws,
    const int*      __restrict__ topk13,    // (B*G, 13)
    const unsigned* __restrict__ inside32,
    const int*      __restrict__ bestg,
    float*          __restrict__ out)
{
    __shared__ int   stopk[NG * KTOP];   // 416 winner anchor ids for this batch
    __shared__ float ssum[4];

    const int tid = threadIdx.x;
    const int b   = blockIdx.y;
    const int a   = blockIdx.x * 256 + tid;

    for (int j = tid; j < NG * KTOP; j += 256)
        stopk[j] = topk13[(size_t)b * NG * KTOP + j];
    __syncthreads();

    bool fg = false;
    if (a < NA) {
        const int i = b * NA + a;
        unsigned m = 0u;
#pragma unroll 4
        for (int g = 0; g < NG; ++g) {
            const int* row = stopk + g * KTOP;
            bool hit = false;
#pragma unroll
            for (int k = 0; k < KTOP; ++k) hit |= (row[k] == a);
            if (hit) m |= (1u << g);
        }
        m &= inside32[i];
        const int cnt = __popc(m);

        int tgt;
        if (cnt > 1)       { tgt = bestg[i];     fg = true;  }
        else if (cnt == 1) { tgt = __ffs(m) - 1; fg = true;  }
        else               { tgt = 0;            fg = false; }

        const float f = fg ? 1.0f : 0.0f;
        const float* gb = gt_bboxes + ((size_t)b * NG + tgt) * 4;
        const float gx1 = gb[0], gy1 = gb[1], gx2 = gb[2], gy2 = gb[3];
        *(float4*)(out + (size_t)i * 4) = make_float4(gx1 * f, gy1 * f, gx2 * f, gy2 * f);

        const size_t BA = (size_t)NB * NA;
        out[BA * 4 + i] = fg ? (float)gt_classes[b * NG + tgt] : 0.0f;

        float ts = 0.0f;
        if (fg) {
            // recompute align(a, tgt) with the same expressions/inputs as fusedAB
            const float4 pb = pb_ws[i];
            const float2 ax = aux_ws[i];
            const float areaA = (pb.z - pb.x) * (pb.w - pb.y);
            const float sag   = (gx2 - gx1) * (gy2 - gy1);
            const float ltx = fmaxf(pb.x, gx1), lty = fmaxf(pb.y, gy1);
            const float rbx = fminf(pb.z, gx2), rby = fminf(pb.w, gy2);
            const float w = fmaxf(rbx - ltx, 0.0f), h = fmaxf(rby - lty, 0.0f);
            const float inter = w * h;
            const float iou = inter / (areaA + sag - inter + 1e-7f);
            const int cls = gt_classes[b * NG + tgt];
            const float cv = __expf(preds[(size_t)b * (4 + NC) * NA + (size_t)(4 + cls) * NA + a] - ax.x) * ax.y;
            ts = sqrtf(fmaxf(iou, 1e-12f)) * sqrtf(fmaxf(cv, 1e-12f));
        }
        out[BA * 5 + i] = ts;
        out[BA * 6 + i] = f;
    }

    // fg.sum(): ballot per wave -> LDS -> one atomic per block (exact fp32 ints)
    const unsigned long long ball = __ballot(fg);
    if ((tid & 63) == 0) ssum[tid >> 6] = (float)__popcll(ball);
    __syncthreads();
    if (tid == 0) {
        const float s = ssum[0] + ssum[1] + ssum[2] + ssum[3];
        if (s != 0.0f) atomicAdd(&out[(size_t)NB * NA * 7], s);
    }
}

// ---------------------------------------------------------------------------
extern "C" void kernel_launch(void* const* d_in, const int* in_sizes, int n_in,
                              void* d_out, int out_size, void* d_ws, size_t ws_size,
                              hipStream_t stream) {
    const float* preds         = (const float*)d_in[0];
    const float* gt_bboxes     = (const float*)d_in[1];
    const int*   gt_classes    = (const int*)  d_in[2];
    const float* anchor_points = (const float*)d_in[3];
    // d_in[4] stride_tensor: unused by the reference math

    float* out = (float*)d_out;
    const size_t BA = (size_t)NB * NA;

    // workspace carve-up (16B-aligned first): pb | aux | inside | bestg | candv | candi | topk13
    char* ws = (char*)d_ws;
    size_t off = 0;
    float4*   pb_ws    = (float4*)(ws + off);   off += BA * sizeof(float4);
    float2*   aux_ws   = (float2*)(ws + off);   off += BA * sizeof(float2);
    unsigned* inside32 = (unsigned*)(ws + off); off += BA * sizeof(unsigned);
    int*      bestg    = (int*)(ws + off);      off += BA * sizeof(int);
    float*    candv    = (float*)(ws + off);    off += (size_t)NB * NG * NCAND * sizeof(float);
    int*      candi    = (int*)(ws + off);      off += (size_t)NB * NG * NCAND * sizeof(int);
    int*      topk13   = (int*)(ws + off);

    fusedAB<<<dim3(NCH, NB), 256, 0, stream>>>(preds, gt_bboxes, gt_classes, anchor_points,
                                               pb_ws, aux_ws, inside32, bestg,
                                               candv, candi, out + BA * 7);

    mergeTopK<<<NB * NG / 4, 256, 0, stream>>>(candv, candi, topk13);

    phaseC<<<dim3((NA + 255) / 256, NB), 256, 0, stream>>>(gt_bboxes, gt_classes, preds,
                                                           pb_ws, aux_ws, topk13,
                                                           inside32, bestg, out);
}

// Round 5
// 489.497 us; speedup vs baseline: 1.2227x; 1.2227x over previous
//
#include <hip/hip_runtime.h>
#include <cfloat>
#include <cstdint>

// Problem constants (YOLOv8 640x640 head)
#define NB 64
#define NG 32
#define NC 80
#define NA 8400
#define KTOP 13
#define CHUNK 512
#define NCH 17                 // ceil(NA/CHUNK)
#define NCAND (NCH * KTOP)     // 221 candidates per (b,g)
#define GGRP 8                 // g's per LDS group (4 groups of 8)

// ---------------------------------------------------------------------------
// Fused A+B: per block = (chunk of 512 anchors, batch b).
// 4 passes over g-groups of 8: compute align -> 16 KB LDS -> wave topk per g.
// Writes pb (float4), (mx, 1/denom) (float2), inside32, bestg, candidates.
// ---------------------------------------------------------------------------
__global__ __launch_bounds__(256) void fusedAB(
    const float* __restrict__ preds,          // (B, 84, A)
    const float* __restrict__ gt_bboxes,      // (B, G, 4)
    const int*   __restrict__ gt_classes,     // (B, G)
    const float* __restrict__ anchor_points,  // (A, 2)
    float4*      __restrict__ pb_ws,          // (B*A) decoded boxes
    float2*      __restrict__ aux_ws,         // (B*A) (mx, rdenom)
    unsigned*    __restrict__ inside32,       // (B*A)
    int*         __restrict__ bestg,          // (B*A)
    float*       __restrict__ candv,          // (B*G, NCH, 13)
    int*         __restrict__ candi,          // (B*G, NCH, 13)
    float*       __restrict__ out_sum)        // scalar, zeroed here
{
    __shared__ float sx1[NG], sy1[NG], sx2[NG], sy2[NG], sarea[NG];
    __shared__ int   scls[NG];
    __shared__ float salign[GGRP][CHUNK];     // 16 KB

    const int tid   = threadIdx.x;
    const int chunk = blockIdx.x;
    const int b     = blockIdx.y;
    const int abase = chunk * CHUNK;
    const int a0    = abase + tid * 2;        // 2 anchors per thread (NA even)
    const bool live = (a0 < NA);

    if (tid < NG) {
        const float* gb = gt_bboxes + ((size_t)b * NG + tid) * 4;
        const float x1 = gb[0], y1 = gb[1], x2 = gb[2], y2 = gb[3];
        sx1[tid] = x1; sy1[tid] = y1; sx2[tid] = x2; sy2[tid] = y2;
        sarea[tid] = (x2 - x1) * (y2 - y1);
        scls[tid]  = gt_classes[b * NG + tid];
    }
    if (b == 0 && chunk == 0 && tid == 0) out_sum[0] = 0.0f;
    __syncthreads();

    // ---- per-thread decode + softmax (once) ----
    float axA=0, ayA=0, axB=0, ayB=0;
    float x1A=0, y1A=0, x2A=0, y2A=0, x1B=0, y1B=0, x2B=0, y2B=0;
    float areaA=0, areaB=0, mxA=0, mxB=0, rdA=0, rdB=0;
    const float* cb = nullptr;
    if (live) {
        const float4 ap = *(const float4*)(anchor_points + (size_t)a0 * 2);
        axA = ap.x; ayA = ap.y; axB = ap.z; ayB = ap.w;

        const float* db = preds + (size_t)b * (4 + NC) * NA + a0;
        const float2 dl = *(const float2*)(db);
        const float2 dt = *(const float2*)(db + (size_t)NA);
        const float2 dr = *(const float2*)(db + (size_t)2 * NA);
        const float2 dm = *(const float2*)(db + (size_t)3 * NA);
        x1A = axA - dl.x; y1A = ayA - dt.x; x2A = axA + dr.x; y2A = ayA + dm.x;
        x1B = axB - dl.y; y1B = ayB - dt.y; x2B = axB + dr.y; y2B = ayB + dm.y;
        areaA = (x2A - x1A) * (y2A - y1A);
        areaB = (x2B - x1B) * (y2B - y1B);

        cb = db + (size_t)4 * NA;
        mxA = -FLT_MAX; mxB = -FLT_MAX;
#pragma unroll 8
        for (int c = 0; c < NC; ++c) {
            const float2 v = *(const float2*)(cb + (size_t)c * NA);
            mxA = fmaxf(mxA, v.x); mxB = fmaxf(mxB, v.y);
        }
        float dA = 0.0f, dB = 0.0f;
#pragma unroll 8
        for (int c = 0; c < NC; ++c) {
            const float2 v = *(const float2*)(cb + (size_t)c * NA);
            dA += __expf(v.x - mxA); dB += __expf(v.y - mxB);
        }
        rdA = 1.0f / dA; rdB = 1.0f / dB;
    }

    unsigned insA = 0u, insB = 0u;
    int bgA = 0, bgB = 0;
    float biA = -1.0f, biB = -1.0f;     // strict > keeps first max (jnp.argmax)

    const int lane = tid & 63;
    const int wid  = tid >> 6;

    // ---- 4 groups of 8 g's: compute -> LDS -> per-wave topk ----
    for (int grp = 0; grp < 4; ++grp) {
        if (live) {
            for (int gg = 0; gg < GGRP; ++gg) {
                const int g = grp * GGRP + gg;
                const float bx1 = sx1[g], by1 = sy1[g], bx2 = sx2[g], by2 = sy2[g];
                const float sag = sarea[g];
                const float2 cv2 = *(const float2*)(cb + (size_t)scls[g] * NA);
                float alA, alB;
                {
                    const float ltx = fmaxf(x1A, bx1), lty = fmaxf(y1A, by1);
                    const float rbx = fminf(x2A, bx2), rby = fminf(y2A, by2);
                    const float w = fmaxf(rbx - ltx, 0.0f), h = fmaxf(rby - lty, 0.0f);
                    const float inter = w * h;
                    const float iou = inter / (areaA + sag - inter + 1e-7f);
                    if (iou > biA) { biA = iou; bgA = g; }
                    const float cv = __expf(cv2.x - mxA) * rdA;
                    alA = sqrtf(fmaxf(iou, 1e-12f)) * sqrtf(fmaxf(cv, 1e-12f));
                    const float dmin = fminf(fminf(axA - bx1, ayA - by1), fminf(bx2 - axA, by2 - ayA));
                    if (dmin > 1e-9f) insA |= (1u << g);
                }
                {
                    const float ltx = fmaxf(x1B, bx1), lty = fmaxf(y1B, by1);
                    const float rbx = fminf(x2B, bx2), rby = fminf(y2B, by2);
                    const float w = fmaxf(rbx - ltx, 0.0f), h = fmaxf(rby - lty, 0.0f);
                    const float inter = w * h;
                    const float iou = inter / (areaB + sag - inter + 1e-7f);
                    if (iou > biB) { biB = iou; bgB = g; }
                    const float cv = __expf(cv2.y - mxB) * rdB;
                    alB = sqrtf(fmaxf(iou, 1e-12f)) * sqrtf(fmaxf(cv, 1e-12f));
                    const float dmin = fminf(fminf(axB - bx1, ayB - by1), fminf(bx2 - axB, by2 - ayB));
                    if (dmin > 1e-9f) insB |= (1u << g);
                }
                *(float2*)&salign[gg][tid * 2] = make_float2(alA, alB);
            }
        }
        __syncthreads();

        // topk: wave wid handles gg = wid*2, wid*2+1 of this group
        for (int gi = 0; gi < 2; ++gi) {
            const int gg = wid * 2 + gi;
            const int g  = grp * GGRP + gg;
            float v[8]; int id[8];
#pragma unroll
            for (int j = 0; j < 8; ++j) { v[j] = -FLT_MAX; id[j] = 0x7FFFFFFF; }
            // lane sees exactly 8 slots (ascending index) -> list never overflows
#pragma unroll
            for (int k = 0; k < 8; ++k) {
                const int al = lane + 64 * k;
                const int a  = abase + al;
                const float x = (a < NA) ? salign[gg][al] : -FLT_MAX;
                if (x > v[7]) {
                    int j = 7;
                    while (j > 0 && v[j - 1] < x) { v[j] = v[j - 1]; id[j] = id[j - 1]; --j; }
                    v[j] = x; id[j] = a;
                }
            }
            float rv = -FLT_MAX; int ri = 0x7FFFFFFF;
            int p = 0;
            for (int r = 0; r < KTOP; ++r) {
                const float cvv = (p < 8) ? v[p]  : -FLT_MAX;
                const int   cii = (p < 8) ? id[p] : 0x7FFFFFFF;
                float bv = cvv; int bi = cii;
#pragma unroll
                for (int off = 32; off > 0; off >>= 1) {
                    const float ov = __shfl_xor(bv, off, 64);
                    const int   oi = __shfl_xor(bi, off, 64);
                    if (ov > bv || (ov == bv && oi < bi)) { bv = ov; bi = oi; }
                }
                if (cii == bi && p < 8) ++p;   // unique ids -> exactly one lane pops
                if (lane == r) { rv = bv; ri = bi; }
            }
            if (lane < KTOP) {
                const size_t base = ((size_t)(b * NG + g) * NCH + chunk) * KTOP + lane;
                candv[base] = rv; candi[base] = ri;
            }
        }
        __syncthreads();
    }

    if (live) {
        const int i0 = b * NA + a0;
        pb_ws[i0]     = make_float4(x1A, y1A, x2A, y2A);
        pb_ws[i0 + 1] = make_float4(x1B, y1B, x2B, y2B);
        aux_ws[i0]     = make_float2(mxA, rdA);
        aux_ws[i0 + 1] = make_float2(mxB, rdB);
        *(uint2*)&inside32[i0] = make_uint2(insA, insB);
        *(int2*)&bestg[i0]     = make_int2(bgA, bgB);
    }
}

// ---------------------------------------------------------------------------
// Merge: one wave per (b,g): merge NCH*13=221 candidates -> final top-13
// anchor indices, written as a dense list (plain stores, NO atomics).
// ---------------------------------------------------------------------------
__global__ __launch_bounds__(256) void mergeTopK(
    const float* __restrict__ candv,
    const int*   __restrict__ candi,
    int*         __restrict__ topk13)   // (B*G, 13)
{
    const int tid  = threadIdx.x;
    const int lane = tid & 63;
    const int row  = blockIdx.x * 4 + (tid >> 6);   // b*NG + g
    const size_t base = (size_t)row * NCAND;

    float v[4]; int id[4];
#pragma unroll
    for (int j = 0; j < 4; ++j) { v[j] = -FLT_MAX; id[j] = 0x7FFFFFFF; }
    // lane sees <=4 candidates; lex insertion (val desc, idx asc)
#pragma unroll
    for (int k = 0; k < 4; ++k) {
        const int j0 = lane + 64 * k;
        if (j0 < NCAND) {
            const float x  = candv[base + j0];
            const int   xi = candi[base + j0];
            int j = 3;
            while (j > 0 && (v[j - 1] < x || (v[j - 1] == x && id[j - 1] > xi))) {
                v[j] = v[j - 1]; id[j] = id[j - 1]; --j;
            }
            v[j] = x; id[j] = xi;
        }
    }
    int ri = 0x7FFFFFFF;
    int p = 0;
    for (int r = 0; r < KTOP; ++r) {
        const float cvv = (p < 4) ? v[p]  : -FLT_MAX;
        const int   cii = (p < 4) ? id[p] : 0x7FFFFFFF;
        float bv = cvv; int bi = cii;
#pragma unroll
        for (int off = 32; off > 0; off >>= 1) {
            const float ov = __shfl_xor(bv, off, 64);
            const int   oi = __shfl_xor(bi, off, 64);
            if (ov > bv || (ov == bv && oi < bi)) { bv = ov; bi = oi; }
        }
        if (cii == bi && p < 4) ++p;
        if (lane == r) ri = bi;
    }
    if (lane < KTOP) topk13[(size_t)row * KTOP + lane] = ri;
}

// ---------------------------------------------------------------------------
// Phase C: grid (33, B). Block loads its batch's 32x13 winner indices into
// LDS; each anchor thread rebuilds its selection mask by scanning them.
// out layout: tb (B,A,4) | tc (B,A) | ts (B,A) | fg (B,A) | fg_sum (1)
// ---------------------------------------------------------------------------
__global__ __launch_bounds__(256) void phaseC(
    const float*    __restrict__ gt_bboxes,
    const int*      __restrict__ gt_classes,
    const float*    __restrict__ preds,
    const float4*   __restrict__ pb_ws,
    const float2*   __restrict__ aux_ws,
    const int*      __restrict__ topk13,    // (B*G, 13)
    const unsigned* __restrict__ inside32,
    const int*      __restrict__ bestg,
    float*          __restrict__ out)
{
    __shared__ int   stopk[NG * KTOP];   // 416 winner anchor ids for this batch
    __shared__ float ssum[4];

    const int tid = threadIdx.x;
    const int b   = blockIdx.y;
    const int a   = blockIdx.x * 256 + tid;

    for (int j = tid; j < NG * KTOP; j += 256)
        stopk[j] = topk13[(size_t)b * NG * KTOP + j];
    __syncthreads();

    bool fg = false;
    if (a < NA) {
        const int i = b * NA + a;
        unsigned m = 0u;
#pragma unroll 4
        for (int g = 0; g < NG; ++g) {
            const int* row = stopk + g * KTOP;
            bool hit = false;
#pragma unroll
            for (int k = 0; k < KTOP; ++k) hit |= (row[k] == a);
            if (hit) m |= (1u << g);
        }
        m &= inside32[i];
        const int cnt = __popc(m);

        int tgt;
        if (cnt > 1)       { tgt = bestg[i];     fg = true;  }
        else if (cnt == 1) { tgt = __ffs(m) - 1; fg = true;  }
        else               { tgt = 0;            fg = false; }

        const float f = fg ? 1.0f : 0.0f;
        const float* gb = gt_bboxes + ((size_t)b * NG + tgt) * 4;
        const float gx1 = gb[0], gy1 = gb[1], gx2 = gb[2], gy2 = gb[3];
        *(float4*)(out + (size_t)i * 4) = make_float4(gx1 * f, gy1 * f, gx2 * f, gy2 * f);

        const size_t BA = (size_t)NB * NA;
        out[BA * 4 + i] = fg ? (float)gt_classes[b * NG + tgt] : 0.0f;

        float ts = 0.0f;
        if (fg) {
            // recompute align(a, tgt) with the same expressions/inputs as fusedAB
            const float4 pb = pb_ws[i];
            const float2 ax = aux_ws[i];
            const float areaA = (pb.z - pb.x) * (pb.w - pb.y);
            const float sag   = (gx2 - gx1) * (gy2 - gy1);
            const float ltx = fmaxf(pb.x, gx1), lty = fmaxf(pb.y, gy1);
            const float rbx = fminf(pb.z, gx2), rby = fminf(pb.w, gy2);
            const float w = fmaxf(rbx - ltx, 0.0f), h = fmaxf(rby - lty, 0.0f);
            const float inter = w * h;
            const float iou = inter / (areaA + sag - inter + 1e-7f);
            const int cls = gt_classes[b * NG + tgt];
            const float cv = __expf(preds[(size_t)b * (4 + NC) * NA + (size_t)(4 + cls) * NA + a] - ax.x) * ax.y;
            ts = sqrtf(fmaxf(iou, 1e-12f)) * sqrtf(fmaxf(cv, 1e-12f));
        }
        out[BA * 5 + i] = ts;
        out[BA * 6 + i] = f;
    }

    // fg.sum(): ballot per wave -> LDS -> one atomic per block (exact fp32 ints)
    const unsigned long long ball = __ballot(fg);
    if ((tid & 63) == 0) ssum[tid >> 6] = (float)__popcll(ball);
    __syncthreads();
    if (tid == 0) {
        const float s = ssum[0] + ssum[1] + ssum[2] + ssum[3];
        if (s != 0.0f) atomicAdd(&out[(size_t)NB * NA * 7], s);
    }
}

// ---------------------------------------------------------------------------
extern "C" void kernel_launch(void* const* d_in, const int* in_sizes, int n_in,
                              void* d_out, int out_size, void* d_ws, size_t ws_size,
                              hipStream_t stream) {
    const float* preds         = (const float*)d_in[0];
    const float* gt_bboxes     = (const float*)d_in[1];
    const int*   gt_classes    = (const int*)  d_in[2];
    const float* anchor_points = (const float*)d_in[3];
    // d_in[4] stride_tensor: unused by the reference math

    float* out = (float*)d_out;
    const size_t BA = (size_t)NB * NA;

    // workspace carve-up (16B-aligned first): pb | aux | inside | bestg | candv | candi | topk13
    char* ws = (char*)d_ws;
    size_t off = 0;
    float4*   pb_ws    = (float4*)(ws + off);   off += BA * sizeof(float4);
    float2*   aux_ws   = (float2*)(ws + off);   off += BA * sizeof(float2);
    unsigned* inside32 = (unsigned*)(ws + off); off += BA * sizeof(unsigned);
    int*      bestg    = (int*)(ws + off);      off += BA * sizeof(int);
    float*    candv    = (float*)(ws + off);    off += (size_t)NB * NG * NCAND * sizeof(float);
    int*      candi    = (int*)(ws + off);      off += (size_t)NB * NG * NCAND * sizeof(int);
    int*      topk13   = (int*)(ws + off);

    fusedAB<<<dim3(NCH, NB), 256, 0, stream>>>(preds, gt_bboxes, gt_classes, anchor_points,
                                               pb_ws, aux_ws, inside32, bestg,
                                               candv, candi, out + BA * 7);

    mergeTopK<<<NB * NG / 4, 256, 0, stream>>>(candv, candi, topk13);

    phaseC<<<dim3((NA + 255) / 256, NB), 256, 0, stream>>>(gt_bboxes, gt_classes, preds,
                                                           pb_ws, aux_ws, topk13,
                                                           inside32, bestg, out);
}